// Round 7
// baseline (976.017 us; speedup 1.0000x reference)
//
#include <hip/hip_runtime.h>
#include <math.h>

// StressCapsuleLayer: capsule dynamic routing (3 iters), fused recompute design.
//   x [128][648][16] f32, W [648][32][32][16] f32 -> v [128][32][32] f32
//
// 3 passes over (b,n); u_hat recomputed each pass (never materialized).
//   pass0: c = 1/32 exactly            -> s0 -> v0 = squash(s0)   [pure GEMM]
//   pass1: logit = <u_hat, v0>         -> softmax_j -> s1 -> v1
//   pass2: logit = <u,v0> + <u,v1>     -> softmax_j -> s2 -> v2 = output
//
// R7 changes (LDS amortization + pipeline):
//  - R6 confirmed spill fix (WRITE 428->44MB, 136us/pass). Now LDS-read-bound:
//    every wave reads the full 64KB W tile per n; at 2 b/wave -> 2.65GB/pass
//    = 46us floor. 4 b/thread halves that (u[4][16]; wq feeds 16 FMAs/read).
//  - Double-buffered LDS (2x64KB=128KB): one barrier/iter; next-tile global
//    loads issued BEFORE compute, ds_write after (T14 latency hiding).
//  - launch_bounds(512,2) caps VGPR at 256 (live ~200, no spill); LDS caps
//    occupancy at 1 block/CU anyway, so the extra VGPR is free.
//  - PHASE0 accumulates into s_acc directly (x1/32 pow2-exact at store).
//  - NC=54, grid=216: uniform 12 n-iters/block, no tail imbalance. XCD
//    swizzle dropped (R6 FETCH=38MB proves W is L3-served).
//  - LDS swizzle byte-identical to R5/R6 (verified: 0 conflicts, correct).

#define N_IN 648
#define ELEMS 131072      // 128*32*32 output elements

template <int PHASE>
__global__ __launch_bounds__(512, 2) void caps_pass(
    const float* __restrict__ x,     // [128][648][16]
    const float* __restrict__ W,     // [648][32][32][16]
    const float* __restrict__ v0,    // [128][32][32]  (PHASE>=1)
    const float* __restrict__ v1,    // [128][32][32]  (PHASE==2)
    float* __restrict__ parts,       // [NC][128][32][32] disjoint partial sums
    int nPer)                        // n's per block (648 / NC)
{
  // 2 x 64KB double buffer. W[n]-quad (jj,d,iq) at LDS quad p = c ^ ((c>>6)&7),
  // c = ((d&15)*4+iq)*64 + (d>>4)*32 + jj.   (verified R5/R6: 0 conflicts)
  __shared__ float4 wlds[2][4096];

  const int t = threadIdx.x;
  const int w = t >> 6;   // wave 0..7
  const int l = t & 63;   // lane
  const int j = l & 31;
  const int dblk = l >> 5;

  const int nchunk = blockIdx.x >> 2;   // 0..NC-1
  const int bgroup = blockIdx.x & 3;    // 0..3
  const int n0 = nchunk * nPer;
  const int bA = bgroup * 32 + w * 4;   // this wave's four b's

  // read offsets: quad for kq=(k*4+iq) at byte kq*1024 + offv[kq&7]
  int offv[8];
#pragma unroll
  for (int m = 0; m < 8; ++m) offv[m] = dblk * 512 + 16 * (j ^ m);

  // staging targets: quad g = r*512 + t -> swizzled LDS byte addr
  int stb[8];
#pragma unroll
  for (int r = 0; r < 8; ++r) {
    const int g = r * 512 + t;
    const int jj = g >> 7;
    const int d = (g >> 2) & 31;
    const int iq = g & 3;
    const int c = ((d & 15) * 4 + iq) * 64 + (d >> 4) * 32 + jj;
    stb[r] = 16 * (c ^ ((c >> 6) & 7));
  }

  float s_acc[4][16];
#pragma unroll
  for (int bb = 0; bb < 4; ++bb)
#pragma unroll
    for (int k = 0; k < 16; ++k) s_acc[bb][k] = 0.f;

  // prologue: stage tile n0 into buffer 0
  {
    const float4* Wn = (const float4*)(W + (size_t)n0 * 16384);
    float4 tmp[8];
#pragma unroll
    for (int r = 0; r < 8; ++r) tmp[r] = Wn[r * 512 + t];  // coalesced
#pragma unroll
    for (int r = 0; r < 8; ++r)
      *(float4*)((char*)&wlds[0][0] + stb[r]) = tmp[r];
  }

  int cur = 0;
  for (int nn = 0; nn < nPer; ++nn) {
    const int n = n0 + nn;
    __syncthreads();  // buf[cur] staged & prior reads of buf[cur^1] done

    // issue next tile's global loads now; consumed by ds_write AFTER compute,
    // so HBM/L3 latency hides under the FMA phase (T14 split)
    const bool more = (nn + 1 < nPer);
    float4 tmp[8];
    if (more) {
      const float4* Wn = (const float4*)(W + (size_t)(n + 1) * 16384);
#pragma unroll
      for (int r = 0; r < 8; ++r) tmp[r] = Wn[r * 512 + t];
    }

    const char* buf = (const char*)&wlds[cur][0];

    float u[4][16];
    if (PHASE != 0) {
#pragma unroll
      for (int bb = 0; bb < 4; ++bb)
#pragma unroll
        for (int k = 0; k < 16; ++k) u[bb][k] = 0.f;
    }

#pragma unroll
    for (int iq = 0; iq < 4; ++iq) {
      float4 xv[4];
#pragma unroll
      for (int bb = 0; bb < 4; ++bb)
        xv[bb] = ((const float4*)(x + ((size_t)(bA + bb) * N_IN + n) * 16))[iq];
#pragma unroll
      for (int k = 0; k < 16; ++k) {
        const int kq = k * 4 + iq;
        const float4 wq = *(const float4*)(buf + offv[kq & 7] + kq * 1024);
        if (PHASE == 0) {
#pragma unroll
          for (int bb = 0; bb < 4; ++bb) {
            s_acc[bb][k] = fmaf(wq.x, xv[bb].x, s_acc[bb][k]);
            s_acc[bb][k] = fmaf(wq.y, xv[bb].y, s_acc[bb][k]);
            s_acc[bb][k] = fmaf(wq.z, xv[bb].z, s_acc[bb][k]);
            s_acc[bb][k] = fmaf(wq.w, xv[bb].w, s_acc[bb][k]);
          }
        } else {
#pragma unroll
          for (int bb = 0; bb < 4; ++bb) {
            u[bb][k] = fmaf(wq.x, xv[bb].x, u[bb][k]);
            u[bb][k] = fmaf(wq.y, xv[bb].y, u[bb][k]);
            u[bb][k] = fmaf(wq.z, xv[bb].z, u[bb][k]);
            u[bb][k] = fmaf(wq.w, xv[bb].w, u[bb][k]);
          }
        }
      }
    }

    if (PHASE != 0) {
#pragma unroll
      for (int bb = 0; bb < 4; ++bb) {
        const int b = bA + bb;
        float logit = 0.f;
        {
          const float4* vp = (const float4*)(v0 + (size_t)b * 1024 + j * 32 + dblk * 16);
          float a = 0.f;
#pragma unroll
          for (int q = 0; q < 4; ++q) {
            const float4 vv = vp[q];
            a = fmaf(u[bb][q * 4 + 0], vv.x, a);
            a = fmaf(u[bb][q * 4 + 1], vv.y, a);
            a = fmaf(u[bb][q * 4 + 2], vv.z, a);
            a = fmaf(u[bb][q * 4 + 3], vv.w, a);
          }
          logit += a;
        }
        if (PHASE == 2) {
          const float4* vp = (const float4*)(v1 + (size_t)b * 1024 + j * 32 + dblk * 16);
          float a = 0.f;
#pragma unroll
          for (int q = 0; q < 4; ++q) {
            const float4 vv = vp[q];
            a = fmaf(u[bb][q * 4 + 0], vv.x, a);
            a = fmaf(u[bb][q * 4 + 1], vv.y, a);
            a = fmaf(u[bb][q * 4 + 2], vv.z, a);
            a = fmaf(u[bb][q * 4 + 3], vv.w, a);
          }
          logit += a;
        }
        // full agreement over d: combine the two d-halves
        logit += __shfl_xor(logit, 32);
        // softmax over 32 j's (width-32 butterflies; halves identical)
        float m = logit;
#pragma unroll
        for (int off = 16; off >= 1; off >>= 1) m = fmaxf(m, __shfl_xor(m, off));
        const float e = __expf(logit - m);
        float Z = e;
#pragma unroll
        for (int off = 16; off >= 1; off >>= 1) Z += __shfl_xor(Z, off);
        const float c = e / Z;
#pragma unroll
        for (int k = 0; k < 16; ++k) s_acc[bb][k] = fmaf(c, u[bb][k], s_acc[bb][k]);
      }
    }

    // write next tile into the other buffer (vmcnt drains here, after compute)
    if (more) {
#pragma unroll
      for (int r = 0; r < 8; ++r)
        *(float4*)((char*)&wlds[cur ^ 1][0] + stb[r]) = tmp[r];
    }
    cur ^= 1;
  }

  // disjoint partial store: parts[chunk][b][j][d]
  float* pbase = parts + (size_t)nchunk * ELEMS;
#pragma unroll
  for (int bb = 0; bb < 4; ++bb) {
    const int b = bA + bb;
    float* sp = pbase + (size_t)b * 1024 + j * 32 + dblk * 16;
#pragma unroll
    for (int k = 0; k < 16; ++k)
      sp[k] = (PHASE == 0) ? s_acc[bb][k] * 0.03125f : s_acc[bb][k];
  }
}

// stage B: sum NC partials, then squash over last dim (32) via width-32 shuffle
__global__ void reduce_squash(const float* __restrict__ parts, int NC,
                              float* __restrict__ v) {
  const int e = blockIdx.x * 256 + threadIdx.x;  // rows of 32 align to half-waves
  float s = 0.f;
  for (int c = 0; c < NC; ++c) s += parts[(size_t)c * ELEMS + e];
  float s2 = s * s;
#pragma unroll
  for (int off = 16; off >= 1; off >>= 1) s2 += __shfl_xor(s2, off);
  const float scale = (s2 / (1.0f + s2)) * rsqrtf(s2 + 1e-7f);
  v[e] = s * scale;
}

extern "C" void kernel_launch(void* const* d_in, const int* in_sizes, int n_in,
                              void* d_out, int out_size, void* d_ws, size_t ws_size,
                              hipStream_t stream) {
  const float* x = (const float*)d_in[0];
  const float* W = (const float*)d_in[1];
  float* out = (float*)d_out;

  float* v0 = (float*)d_ws;            // 131072 f32
  float* v1 = v0 + ELEMS;              // 131072 f32
  float* parts = v1 + ELEMS;           // NC * 131072 f32

  // choose NC (divisor of 648) from available workspace; deterministic since
  // ws_size is fixed. Prefer 54: grid = 4*54 = 216 uniform blocks (1/CU).
  int avail = 0;
  if (ws_size / 4 > 2 * (size_t)ELEMS)
    avail = (int)((ws_size / 4 - 2 * (size_t)ELEMS) / ELEMS);
  const int ladder[] = {54, 36, 27, 24, 18, 12, 9, 8, 6, 4, 3, 2, 1};
  int NC = 1;
  for (int i = 0; i < 13; ++i)
    if (ladder[i] <= avail) { NC = ladder[i]; break; }
  const int nPer = N_IN / NC;

  const dim3 grid(NC * 4);   // 4 b-groups of 32
  const dim3 blk(512);

  caps_pass<0><<<grid, blk, 0, stream>>>(x, W, nullptr, nullptr, parts, nPer);
  reduce_squash<<<512, 256, 0, stream>>>(parts, NC, v0);

  caps_pass<1><<<grid, blk, 0, stream>>>(x, W, v0, nullptr, parts, nPer);
  reduce_squash<<<512, 256, 0, stream>>>(parts, NC, v1);

  caps_pass<2><<<grid, blk, 0, stream>>>(x, W, v0, v1, parts, nPer);
  reduce_squash<<<512, 256, 0, stream>>>(parts, NC, out);
}